// Round 1
// baseline (763.901 us; speedup 1.0000x reference)
//
#include <hip/hip_runtime.h>
#include <math.h>

#define N_NODES 20000
#define N_EDGES 320000
#define EN (N_EDGES + N_NODES)   // edges + self loops = 340000
#define DIM 128
#define HEADS 4
#define DH (HEADS * DIM)         // 512
#define NEG_SLOPE 0.2f
#define BN_EPS 1e-5f

__device__ __forceinline__ float lrelu(float x) { return x > 0.f ? x : NEG_SLOPE * x; }

// ---------------- graph build ----------------

__global__ __launch_bounds__(256) void build_edges_kernel(
    const void* __restrict__ ei_raw, int* __restrict__ src32,
    int* __restrict__ dst32, int* __restrict__ deg) {
  int e = blockIdx.x * 256 + threadIdx.x;
  if (e >= EN) return;
  const long long* ei64 = (const long long*)ei_raw;
  const int* ei32 = (const int*)ei_raw;
  // dtype sniff: reference says int64, but JAX without x64 silently gives int32.
  // If the first 4 int64 interpretations are valid node ids, it's int64
  // (int32 pairs packed into int64 are >= 2^32 unless the high word is 0).
  bool is64 = true;
#pragma unroll
  for (int k = 0; k < 4; ++k) {
    long long v = ei64[k];
    if (v < 0 || v >= N_NODES) is64 = false;
  }
  int s, d;
  if (e < N_EDGES) {
    if (is64) { s = (int)ei64[e]; d = (int)ei64[N_EDGES + e]; }
    else      { s = ei32[e];      d = ei32[N_EDGES + e]; }
  } else {
    s = d = e - N_EDGES;  // self loop
  }
  src32[e] = s;
  dst32[e] = d;
  atomicAdd(&deg[d], 1);
}

__global__ __launch_bounds__(1024) void scan_kernel(
    const int* __restrict__ deg, int* __restrict__ off) {
  __shared__ int sums[1024];
  const int tid = threadIdx.x;
  const int chunk = (N_NODES + 1023) / 1024;  // 20
  int start = tid * chunk;
  int end = start + chunk; if (end > N_NODES) end = N_NODES;
  int s = 0;
  for (int i = start; i < end && i < N_NODES; ++i) s += deg[i];
  sums[tid] = s;
  __syncthreads();
  for (int st = 1; st < 1024; st <<= 1) {
    int t = (tid >= st) ? sums[tid - st] : 0;
    __syncthreads();
    sums[tid] += t;
    __syncthreads();
  }
  int run = sums[tid] - s;  // exclusive prefix of this thread's chunk
  for (int i = start; i < end && i < N_NODES; ++i) { off[i] = run; run += deg[i]; }
  if (tid == 1023) off[N_NODES] = sums[1023];
}

__global__ __launch_bounds__(256) void scatter_kernel(
    const int* __restrict__ src32, const int* __restrict__ dst32,
    const int* __restrict__ off, int* __restrict__ cursor,
    int* __restrict__ csrc) {
  int e = blockIdx.x * 256 + threadIdx.x;
  if (e >= EN) return;
  int d = dst32[e];
  int pos = atomicAdd(&cursor[d], 1);
  csrc[off[d] + pos] = src32[e];
}

// ---------------- GEMM: [M x 128] @ [128 x N] -> [M x N], fp32 ----------------

__global__ __launch_bounds__(256) void gemm128_kernel(
    const float* __restrict__ A, const float* __restrict__ B,
    float* __restrict__ C, int M, int N) {
  __shared__ float As[64][68];
  __shared__ float Bs[64][68];
  int tid = threadIdx.x;
  int ty = tid >> 4, tx = tid & 15;
  int brow = blockIdx.x * 64, bcol = blockIdx.y * 64;
  float acc[4][4] = {};
  for (int k0 = 0; k0 < 128; k0 += 64) {
    for (int i = tid; i < 64 * 16; i += 256) {
      int r = i >> 4, c4 = i & 15;
      int row = brow + r;
      float4 v = make_float4(0.f, 0.f, 0.f, 0.f);
      if (row < M) v = *(const float4*)&A[(size_t)row * 128 + k0 + c4 * 4];
      *(float4*)&As[r][c4 * 4] = v;
    }
    for (int i = tid; i < 64 * 16; i += 256) {
      int r = i >> 4, c4 = i & 15;
      float4 v = *(const float4*)&B[(size_t)(k0 + r) * N + bcol + c4 * 4];
      *(float4*)&Bs[r][c4 * 4] = v;
    }
    __syncthreads();
#pragma unroll
    for (int k = 0; k < 64; ++k) {
      float a[4], b[4];
#pragma unroll
      for (int i = 0; i < 4; ++i) a[i] = As[ty * 4 + i][k];
#pragma unroll
      for (int j = 0; j < 4; ++j) b[j] = Bs[k][tx * 4 + j];
#pragma unroll
      for (int i = 0; i < 4; ++i)
#pragma unroll
        for (int j = 0; j < 4; ++j) acc[i][j] += a[i] * b[j];
    }
    __syncthreads();
  }
#pragma unroll
  for (int i = 0; i < 4; ++i) {
    int row = brow + ty * 4 + i;
    if (row < M) {
      float4 v = make_float4(acc[i][0], acc[i][1], acc[i][2], acc[i][3]);
      *(float4*)&C[(size_t)row * N + bcol + tx * 4] = v;
    }
  }
}

// ---------------- attention coefficients ----------------

// one block per node; wave w (of 4) handles head w; C=128 -> 2 elems/lane
__global__ __launch_bounds__(256) void alpha_kernel(
    const float* __restrict__ H, const float* __restrict__ a_src,
    const float* __restrict__ a_dst, float* __restrict__ as_,
    float* __restrict__ ad_) {
  int n = blockIdx.x;
  int head = threadIdx.x >> 6;
  int lane = threadIdx.x & 63;
  const float* hp = H + (size_t)n * DH + head * DIM;
  float h0 = hp[lane], h1 = hp[lane + 64];
  float s = h0 * a_src[head * DIM + lane] + h1 * a_src[head * DIM + lane + 64];
  float d = h0 * a_dst[head * DIM + lane] + h1 * a_dst[head * DIM + lane + 64];
#pragma unroll
  for (int o = 32; o > 0; o >>= 1) {
    s += __shfl_xor(s, o);
    d += __shfl_xor(d, o);
  }
  if (lane == 0) {
    as_[n * 4 + head] = s;
    ad_[n * 4 + head] = d;
  }
}

// segment softmax, one wave per destination node (4 nodes / block)
__global__ __launch_bounds__(256) void softmax_kernel(
    const float* __restrict__ as_, const float* __restrict__ ad_,
    const int* __restrict__ off, const int* __restrict__ csrc,
    float* __restrict__ alpha) {
  int n = blockIdx.x * 4 + (threadIdx.x >> 6);
  if (n >= N_NODES) return;
  int lane = threadIdx.x & 63;
  int e0 = off[n], e1 = off[n + 1];
  float4 ad = *(const float4*)&ad_[n * 4];
  float m0 = -1e30f, m1 = -1e30f, m2 = -1e30f, m3 = -1e30f;
  for (int i = e0 + lane; i < e1; i += 64) {
    int s = csrc[i];
    float4 av = *(const float4*)&as_[s * 4];
    float l0 = lrelu(av.x + ad.x), l1 = lrelu(av.y + ad.y);
    float l2 = lrelu(av.z + ad.z), l3 = lrelu(av.w + ad.w);
    ((float4*)alpha)[i] = make_float4(l0, l1, l2, l3);
    m0 = fmaxf(m0, l0); m1 = fmaxf(m1, l1);
    m2 = fmaxf(m2, l2); m3 = fmaxf(m3, l3);
  }
#pragma unroll
  for (int o = 32; o > 0; o >>= 1) {
    m0 = fmaxf(m0, __shfl_xor(m0, o)); m1 = fmaxf(m1, __shfl_xor(m1, o));
    m2 = fmaxf(m2, __shfl_xor(m2, o)); m3 = fmaxf(m3, __shfl_xor(m3, o));
  }
  float z0 = 0.f, z1 = 0.f, z2 = 0.f, z3 = 0.f;
  for (int i = e0 + lane; i < e1; i += 64) {
    float4 l = ((const float4*)alpha)[i];
    float p0 = expf(l.x - m0), p1 = expf(l.y - m1);
    float p2 = expf(l.z - m2), p3 = expf(l.w - m3);
    ((float4*)alpha)[i] = make_float4(p0, p1, p2, p3);
    z0 += p0; z1 += p1; z2 += p2; z3 += p3;
  }
#pragma unroll
  for (int o = 32; o > 0; o >>= 1) {
    z0 += __shfl_xor(z0, o); z1 += __shfl_xor(z1, o);
    z2 += __shfl_xor(z2, o); z3 += __shfl_xor(z3, o);
  }
  float r0 = 1.f / (z0 + 1e-16f), r1 = 1.f / (z1 + 1e-16f);
  float r2 = 1.f / (z2 + 1e-16f), r3 = 1.f / (z3 + 1e-16f);
  for (int i = e0 + lane; i < e1; i += 64) {
    float4 p = ((const float4*)alpha)[i];
    ((float4*)alpha)[i] = make_float4(p.x * r0, p.y * r1, p.z * r2, p.w * r3);
  }
}

// weighted aggregation + head mean + bias; one block (256 thr) per dst node.
// thread t covers (head t>>7, c t&127) and (head (t>>7)+2, same c).
__global__ __launch_bounds__(256) void agg_kernel(
    const float* __restrict__ H, const float* __restrict__ alpha,
    const int* __restrict__ off, const int* __restrict__ csrc,
    const float* __restrict__ bias, float* __restrict__ out) {
  int n = blockIdx.x;
  int tid = threadIdx.x;
  int h0 = tid >> 7;  // 0 or 1
  int c = tid & 127;
  int e0 = off[n], e1 = off[n + 1];
  float acc0 = 0.f, acc1 = 0.f;
  for (int i = e0; i < e1; ++i) {
    int s = csrc[i];
    float w0 = alpha[(size_t)i * 4 + h0];
    float w1 = alpha[(size_t)i * 4 + h0 + 2];
    const float* hp = H + (size_t)s * DH;
    acc0 += w0 * hp[h0 * DIM + c];
    acc1 += w1 * hp[(h0 + 2) * DIM + c];
  }
  __shared__ float red[256];
  red[tid] = acc0 + acc1;
  __syncthreads();
  if (tid < DIM) {
    out[(size_t)n * DIM + tid] = 0.25f * (red[tid] + red[tid + DIM]) + bias[tid];
  }
}

// ---------------- batchnorm ----------------

__global__ __launch_bounds__(256) void bn_stats_kernel(
    const float* __restrict__ X, float* __restrict__ stats) {
  int c = threadIdx.x & 127;
  int half = threadIdx.x >> 7;
  float s = 0.f, s2 = 0.f;
  for (int r = blockIdx.x * 2 + half; r < N_NODES; r += gridDim.x * 2) {
    float v = X[(size_t)r * DIM + c];
    s += v;
    s2 += v * v;
  }
  atomicAdd(&stats[c], s);
  atomicAdd(&stats[DIM + c], s2);
}

__global__ __launch_bounds__(256) void bn_apply_kernel(
    float* __restrict__ X, const float* __restrict__ stats,
    const float* __restrict__ gamma, const float* __restrict__ beta) {
  int idx = blockIdx.x * 256 + threadIdx.x;
  if (idx >= N_NODES * DIM) return;
  int c = idx & 127;
  const float invN = 1.f / (float)N_NODES;
  float mean = stats[c] * invN;
  float var = stats[DIM + c] * invN - mean * mean;
  float scale = gamma[c] * rsqrtf(var + BN_EPS);
  float shift = beta[c] - mean * scale;
  float v = X[idx] * scale + shift;
  X[idx] = fmaxf(v, 0.f);
}

// ---------------- launch ----------------

extern "C" void kernel_launch(void* const* d_in, const int* in_sizes, int n_in,
                              void* d_out, int out_size, void* d_ws, size_t ws_size,
                              hipStream_t stream) {
  (void)in_sizes; (void)n_in; (void)out_size; (void)ws_size;
  const float* x = (const float*)d_in[0];
  const void* ei = d_in[1];
  const float* eattr = (const float*)d_in[2];
  const float* W[3]    = {(const float*)d_in[3],  (const float*)d_in[7],  (const float*)d_in[11]};
  const float* asrc[3] = {(const float*)d_in[4],  (const float*)d_in[8],  (const float*)d_in[12]};
  const float* adst[3] = {(const float*)d_in[5],  (const float*)d_in[9],  (const float*)d_in[13]};
  const float* bias[3] = {(const float*)d_in[6],  (const float*)d_in[10], (const float*)d_in[14]};
  const float* gamma[2] = {(const float*)d_in[15], (const float*)d_in[17]};
  const float* beta[2]  = {(const float*)d_in[16], (const float*)d_in[18]};

  char* ws = (char*)d_ws;
  size_t o = 0;
  auto alloc = [&](size_t bytes) -> void* {
    void* p = ws + o;
    o += (bytes + 255) & ~(size_t)255;
    return p;
  };
  // zero-init region first (deg, cursor, bn stats)
  int* deg      = (int*)alloc(N_NODES * 4);
  int* cursor   = (int*)alloc(N_NODES * 4);
  float* stats0 = (float*)alloc(2 * DIM * 4);
  float* stats1 = (float*)alloc(2 * DIM * 4);
  size_t zero_bytes = o;
  int* off    = (int*)alloc((N_NODES + 1) * 4);
  int* src32  = (int*)alloc((size_t)EN * 4);
  int* dst32  = (int*)alloc((size_t)EN * 4);
  int* csrc   = (int*)alloc((size_t)EN * 4);
  float* alpha = (float*)alloc((size_t)EN * 4 * 4);
  float* Hb    = (float*)alloc((size_t)N_NODES * DH * 4);
  float* Ob    = (float*)alloc((size_t)N_NODES * DIM * 4);
  float* as_   = (float*)alloc((size_t)N_NODES * 4 * 4);
  float* ad_   = (float*)alloc((size_t)N_NODES * 4 * 4);

  hipMemsetAsync(d_ws, 0, zero_bytes, stream);

  build_edges_kernel<<<(EN + 255) / 256, 256, 0, stream>>>(ei, src32, dst32, deg);
  scan_kernel<<<1, 1024, 0, stream>>>(deg, off);
  scatter_kernel<<<(EN + 255) / 256, 256, 0, stream>>>(src32, dst32, off, cursor, csrc);

  const float* in_ptr = x;
  for (int L = 0; L < 3; ++L) {
    gemm128_kernel<<<dim3((N_NODES + 63) / 64, DH / 64), 256, 0, stream>>>(
        in_ptr, W[L], Hb, N_NODES, DH);
    alpha_kernel<<<N_NODES, 256, 0, stream>>>(Hb, asrc[L], adst[L], as_, ad_);
    softmax_kernel<<<N_NODES / 4, 256, 0, stream>>>(as_, ad_, off, csrc, alpha);
    float* outp = (L == 2) ? (float*)d_out : Ob;
    agg_kernel<<<N_NODES, 256, 0, stream>>>(Hb, alpha, off, csrc, bias[L], outp);
    if (L < 2) {
      float* st = (L == 0) ? stats0 : stats1;
      bn_stats_kernel<<<64, 256, 0, stream>>>(Ob, st);
      bn_apply_kernel<<<(N_NODES * DIM + 255) / 256, 256, 0, stream>>>(
          Ob, st, gamma[L], beta[L]);
      in_ptr = Ob;
    }
  }

  // edge_attr passthrough (second tuple element)
  hipMemcpyAsync((float*)d_out + (size_t)N_NODES * DIM, eattr,
                 (size_t)N_EDGES * 16 * 4, hipMemcpyDeviceToDevice, stream);
}

// Round 2
// 629.283 us; speedup vs baseline: 1.2139x; 1.2139x over previous
//
#include <hip/hip_runtime.h>
#include <hip/hip_fp16.h>
#include <math.h>

#define N_NODES 20000
#define N_EDGES 320000
#define EN (N_EDGES + N_NODES)   // edges + self loops = 340000
#define DIM 128
#define HEADS 4
#define DH (HEADS * DIM)         // 512
#define NEG_SLOPE 0.2f
#define BN_EPS 1e-5f

__device__ __forceinline__ float lrelu(float x) { return x > 0.f ? x : NEG_SLOPE * x; }

// ---------------- graph build ----------------

__global__ __launch_bounds__(256) void build_edges_kernel(
    const void* __restrict__ ei_raw, int* __restrict__ src32,
    int* __restrict__ dst32, int* __restrict__ deg) {
  int e = blockIdx.x * 256 + threadIdx.x;
  if (e >= EN) return;
  const long long* ei64 = (const long long*)ei_raw;
  const int* ei32 = (const int*)ei_raw;
  bool is64 = true;
#pragma unroll
  for (int k = 0; k < 4; ++k) {
    long long v = ei64[k];
    if (v < 0 || v >= N_NODES) is64 = false;
  }
  int s, d;
  if (e < N_EDGES) {
    if (is64) { s = (int)ei64[e]; d = (int)ei64[N_EDGES + e]; }
    else      { s = ei32[e];      d = ei32[N_EDGES + e]; }
  } else {
    s = d = e - N_EDGES;  // self loop
  }
  src32[e] = s;
  dst32[e] = d;
  atomicAdd(&deg[d], 1);
}

__global__ __launch_bounds__(1024) void scan_kernel(
    const int* __restrict__ deg, int* __restrict__ off) {
  __shared__ int sums[1024];
  const int tid = threadIdx.x;
  const int chunk = (N_NODES + 1023) / 1024;  // 20
  int start = tid * chunk;
  int end = start + chunk; if (end > N_NODES) end = N_NODES;
  int s = 0;
  for (int i = start; i < end && i < N_NODES; ++i) s += deg[i];
  sums[tid] = s;
  __syncthreads();
  for (int st = 1; st < 1024; st <<= 1) {
    int t = (tid >= st) ? sums[tid - st] : 0;
    __syncthreads();
    sums[tid] += t;
    __syncthreads();
  }
  int run = sums[tid] - s;  // exclusive prefix of this thread's chunk
  for (int i = start; i < end && i < N_NODES; ++i) { off[i] = run; run += deg[i]; }
  if (tid == 1023) off[N_NODES] = sums[1023];
}

__global__ __launch_bounds__(256) void scatter_kernel(
    const int* __restrict__ src32, const int* __restrict__ dst32,
    const int* __restrict__ off, int* __restrict__ cursor,
    int* __restrict__ csrc) {
  int e = blockIdx.x * 256 + threadIdx.x;
  if (e >= EN) return;
  int d = dst32[e];
  int pos = atomicAdd(&cursor[d], 1);
  csrc[off[d] + pos] = src32[e];
}

// ---------------- GEMM: [M x 128] @ [128 x 512] -> fp16 H ----------------

__global__ __launch_bounds__(256) void gemm128_kernel(
    const float* __restrict__ A, const float* __restrict__ B,
    ushort* __restrict__ H16, int M, int N) {
  __shared__ float As[64][68];
  __shared__ float Bs[64][68];
  int tid = threadIdx.x;
  int ty = tid >> 4, tx = tid & 15;
  int brow = blockIdx.x * 64, bcol = blockIdx.y * 64;
  float acc[4][4] = {};
  for (int k0 = 0; k0 < 128; k0 += 64) {
    for (int i = tid; i < 64 * 16; i += 256) {
      int r = i >> 4, c4 = i & 15;
      int row = brow + r;
      float4 v = make_float4(0.f, 0.f, 0.f, 0.f);
      if (row < M) v = *(const float4*)&A[(size_t)row * 128 + k0 + c4 * 4];
      *(float4*)&As[r][c4 * 4] = v;
    }
    for (int i = tid; i < 64 * 16; i += 256) {
      int r = i >> 4, c4 = i & 15;
      float4 v = *(const float4*)&B[(size_t)(k0 + r) * N + bcol + c4 * 4];
      *(float4*)&Bs[r][c4 * 4] = v;
    }
    __syncthreads();
#pragma unroll
    for (int k = 0; k < 64; ++k) {
      float a[4], b[4];
#pragma unroll
      for (int i = 0; i < 4; ++i) a[i] = As[ty * 4 + i][k];
#pragma unroll
      for (int j = 0; j < 4; ++j) b[j] = Bs[k][tx * 4 + j];
#pragma unroll
      for (int i = 0; i < 4; ++i)
#pragma unroll
        for (int j = 0; j < 4; ++j) acc[i][j] += a[i] * b[j];
    }
    __syncthreads();
  }
#pragma unroll
  for (int i = 0; i < 4; ++i) {
    int row = brow + ty * 4 + i;
    if (row < M) {
      union { __half2 h2[2]; uint2 u; } pk;
      pk.h2[0] = __floats2half2_rn(acc[i][0], acc[i][1]);
      pk.h2[1] = __floats2half2_rn(acc[i][2], acc[i][3]);
      *(uint2*)&H16[(size_t)row * N + bcol + tx * 4] = pk.u;
    }
  }
}

// ---------------- attention coefficients ----------------

// one block per node; wave w (of 4) handles head w; 64 lanes x half2 = 128 ch
__global__ __launch_bounds__(256) void alpha_kernel(
    const ushort* __restrict__ H16, const float* __restrict__ a_src,
    const float* __restrict__ a_dst, float* __restrict__ as_,
    float* __restrict__ ad_) {
  int n = blockIdx.x;
  int head = threadIdx.x >> 6;
  int lane = threadIdx.x & 63;
  const __half2* hp = (const __half2*)(H16 + (size_t)n * DH) + head * 64 + lane;
  float2 h = __half22float2(*hp);
  float s = h.x * a_src[head * DIM + 2 * lane] + h.y * a_src[head * DIM + 2 * lane + 1];
  float d = h.x * a_dst[head * DIM + 2 * lane] + h.y * a_dst[head * DIM + 2 * lane + 1];
#pragma unroll
  for (int o = 32; o > 0; o >>= 1) {
    s += __shfl_xor(s, o);
    d += __shfl_xor(d, o);
  }
  if (lane == 0) {
    as_[n * 4 + head] = s;
    ad_[n * 4 + head] = d;
  }
}

// segment softmax, one wave per destination node (4 nodes / block)
// writes NORMALIZED alpha. Register fast path for deg <= 64 (one edge/lane).
__global__ __launch_bounds__(256) void softmax_kernel(
    const float* __restrict__ as_, const float* __restrict__ ad_,
    const int* __restrict__ off, const int* __restrict__ csrc,
    float* __restrict__ alpha) {
  int n = blockIdx.x * 4 + (threadIdx.x >> 6);
  if (n >= N_NODES) return;
  int lane = threadIdx.x & 63;
  int e0 = off[n], e1 = off[n + 1];
  float4 ad = *(const float4*)&ad_[n * 4];
  int deg = e1 - e0;
  if (deg <= 64) {
    int i = e0 + lane;
    bool valid = i < e1;
    float l0 = -1e30f, l1 = -1e30f, l2 = -1e30f, l3 = -1e30f;
    if (valid) {
      int s = csrc[i];
      float4 av = *(const float4*)&as_[s * 4];
      l0 = lrelu(av.x + ad.x); l1 = lrelu(av.y + ad.y);
      l2 = lrelu(av.z + ad.z); l3 = lrelu(av.w + ad.w);
    }
    float m0 = l0, m1 = l1, m2 = l2, m3 = l3;
#pragma unroll
    for (int o = 32; o > 0; o >>= 1) {
      m0 = fmaxf(m0, __shfl_xor(m0, o)); m1 = fmaxf(m1, __shfl_xor(m1, o));
      m2 = fmaxf(m2, __shfl_xor(m2, o)); m3 = fmaxf(m3, __shfl_xor(m3, o));
    }
    float p0 = valid ? expf(l0 - m0) : 0.f;
    float p1 = valid ? expf(l1 - m1) : 0.f;
    float p2 = valid ? expf(l2 - m2) : 0.f;
    float p3 = valid ? expf(l3 - m3) : 0.f;
    float z0 = p0, z1 = p1, z2 = p2, z3 = p3;
#pragma unroll
    for (int o = 32; o > 0; o >>= 1) {
      z0 += __shfl_xor(z0, o); z1 += __shfl_xor(z1, o);
      z2 += __shfl_xor(z2, o); z3 += __shfl_xor(z3, o);
    }
    if (valid) {
      float4 r = make_float4(p0 / (z0 + 1e-16f), p1 / (z1 + 1e-16f),
                             p2 / (z2 + 1e-16f), p3 / (z3 + 1e-16f));
      ((float4*)alpha)[i] = r;
    }
    return;
  }
  // generic path (rare)
  float m0 = -1e30f, m1 = -1e30f, m2 = -1e30f, m3 = -1e30f;
  for (int i = e0 + lane; i < e1; i += 64) {
    int s = csrc[i];
    float4 av = *(const float4*)&as_[s * 4];
    float l0 = lrelu(av.x + ad.x), l1 = lrelu(av.y + ad.y);
    float l2 = lrelu(av.z + ad.z), l3 = lrelu(av.w + ad.w);
    ((float4*)alpha)[i] = make_float4(l0, l1, l2, l3);
    m0 = fmaxf(m0, l0); m1 = fmaxf(m1, l1);
    m2 = fmaxf(m2, l2); m3 = fmaxf(m3, l3);
  }
#pragma unroll
  for (int o = 32; o > 0; o >>= 1) {
    m0 = fmaxf(m0, __shfl_xor(m0, o)); m1 = fmaxf(m1, __shfl_xor(m1, o));
    m2 = fmaxf(m2, __shfl_xor(m2, o)); m3 = fmaxf(m3, __shfl_xor(m3, o));
  }
  float z0 = 0.f, z1 = 0.f, z2 = 0.f, z3 = 0.f;
  for (int i = e0 + lane; i < e1; i += 64) {
    float4 l = ((const float4*)alpha)[i];
    float p0 = expf(l.x - m0), p1 = expf(l.y - m1);
    float p2 = expf(l.z - m2), p3 = expf(l.w - m3);
    ((float4*)alpha)[i] = make_float4(p0, p1, p2, p3);
    z0 += p0; z1 += p1; z2 += p2; z3 += p3;
  }
#pragma unroll
  for (int o = 32; o > 0; o >>= 1) {
    z0 += __shfl_xor(z0, o); z1 += __shfl_xor(z1, o);
    z2 += __shfl_xor(z2, o); z3 += __shfl_xor(z3, o);
  }
  float r0 = 1.f / (z0 + 1e-16f), r1 = 1.f / (z1 + 1e-16f);
  float r2 = 1.f / (z2 + 1e-16f), r3 = 1.f / (z3 + 1e-16f);
  for (int i = e0 + lane; i < e1; i += 64) {
    float4 p = ((const float4*)alpha)[i];
    ((float4*)alpha)[i] = make_float4(p.x * r0, p.y * r1, p.z * r2, p.w * r3);
  }
}

// weighted aggregation + head mean + bias; one block (256 thr) per dst node.
// wave w handles head w; lane covers half2 channel pair. alpha load is a
// wave-uniform broadcast; H load is 512B contiguous per wave.
__global__ __launch_bounds__(256) void agg_kernel(
    const ushort* __restrict__ H16, const float* __restrict__ alpha,
    const int* __restrict__ off, const int* __restrict__ csrc,
    const float* __restrict__ bias, float* __restrict__ out) {
  int n = blockIdx.x;
  int tid = threadIdx.x;
  int head = tid >> 6;    // 0..3
  int cp = tid & 63;      // half2 index within head
  int e0 = off[n], e1 = off[n + 1];
  const __half2* Hb = (const __half2*)H16;
  float ax = 0.f, ay = 0.f;
  int i = e0;
  for (; i + 1 < e1; i += 2) {
    int s0 = csrc[i], s1 = csrc[i + 1];
    float w0 = alpha[(size_t)i * 4 + head];
    float w1 = alpha[(size_t)(i + 1) * 4 + head];
    __half2 h0 = Hb[(size_t)s0 * 256 + head * 64 + cp];
    __half2 h1 = Hb[(size_t)s1 * 256 + head * 64 + cp];
    float2 f0 = __half22float2(h0);
    float2 f1 = __half22float2(h1);
    ax += w0 * f0.x + w1 * f1.x;
    ay += w0 * f0.y + w1 * f1.y;
  }
  if (i < e1) {
    int s0 = csrc[i];
    float w0 = alpha[(size_t)i * 4 + head];
    float2 f0 = __half22float2(Hb[(size_t)s0 * 256 + head * 64 + cp]);
    ax += w0 * f0.x;
    ay += w0 * f0.y;
  }
  __shared__ float2 red[256];
  red[tid] = make_float2(ax, ay);
  __syncthreads();
  if (tid < 64) {
    float2 r0 = red[tid], r1 = red[tid + 64], r2 = red[tid + 128], r3 = red[tid + 192];
    float o0 = 0.25f * (r0.x + r1.x + r2.x + r3.x) + bias[2 * tid];
    float o1 = 0.25f * (r0.y + r1.y + r2.y + r3.y) + bias[2 * tid + 1];
    *(float2*)&out[(size_t)n * DIM + 2 * tid] = make_float2(o0, o1);
  }
}

// ---------------- batchnorm ----------------

__global__ __launch_bounds__(256) void bn_stats_kernel(
    const float* __restrict__ X, float* __restrict__ stats) {
  int c = threadIdx.x & 127;
  int half = threadIdx.x >> 7;
  float s = 0.f, s2 = 0.f;
  for (int r = blockIdx.x * 2 + half; r < N_NODES; r += gridDim.x * 2) {
    float v = X[(size_t)r * DIM + c];
    s += v;
    s2 += v * v;
  }
  atomicAdd(&stats[c], s);
  atomicAdd(&stats[DIM + c], s2);
}

__global__ __launch_bounds__(256) void bn_apply_kernel(
    float* __restrict__ X, const float* __restrict__ stats,
    const float* __restrict__ gamma, const float* __restrict__ beta) {
  int idx = blockIdx.x * 256 + threadIdx.x;
  if (idx >= N_NODES * DIM) return;
  int c = idx & 127;
  const float invN = 1.f / (float)N_NODES;
  float mean = stats[c] * invN;
  float var = stats[DIM + c] * invN - mean * mean;
  float scale = gamma[c] * rsqrtf(var + BN_EPS);
  float shift = beta[c] - mean * scale;
  float v = X[idx] * scale + shift;
  X[idx] = fmaxf(v, 0.f);
}

// ---------------- launch ----------------

extern "C" void kernel_launch(void* const* d_in, const int* in_sizes, int n_in,
                              void* d_out, int out_size, void* d_ws, size_t ws_size,
                              hipStream_t stream) {
  (void)in_sizes; (void)n_in; (void)out_size; (void)ws_size;
  const float* x = (const float*)d_in[0];
  const void* ei = d_in[1];
  const float* eattr = (const float*)d_in[2];
  const float* W[3]    = {(const float*)d_in[3],  (const float*)d_in[7],  (const float*)d_in[11]};
  const float* asrc[3] = {(const float*)d_in[4],  (const float*)d_in[8],  (const float*)d_in[12]};
  const float* adst[3] = {(const float*)d_in[5],  (const float*)d_in[9],  (const float*)d_in[13]};
  const float* bias[3] = {(const float*)d_in[6],  (const float*)d_in[10], (const float*)d_in[14]};
  const float* gamma[2] = {(const float*)d_in[15], (const float*)d_in[17]};
  const float* beta[2]  = {(const float*)d_in[16], (const float*)d_in[18]};

  char* ws = (char*)d_ws;
  size_t o = 0;
  auto alloc = [&](size_t bytes) -> void* {
    void* p = ws + o;
    o += (bytes + 255) & ~(size_t)255;
    return p;
  };
  // zero-init region first (deg, cursor, bn stats)
  int* deg      = (int*)alloc(N_NODES * 4);
  int* cursor   = (int*)alloc(N_NODES * 4);
  float* stats0 = (float*)alloc(2 * DIM * 4);
  float* stats1 = (float*)alloc(2 * DIM * 4);
  size_t zero_bytes = o;
  int* off    = (int*)alloc((N_NODES + 1) * 4);
  int* src32  = (int*)alloc((size_t)EN * 4);
  int* dst32  = (int*)alloc((size_t)EN * 4);
  int* csrc   = (int*)alloc((size_t)EN * 4);
  float* alpha = (float*)alloc((size_t)EN * 4 * 4);
  ushort* H16  = (ushort*)alloc((size_t)N_NODES * DH * 2);
  float* Ob    = (float*)alloc((size_t)N_NODES * DIM * 4);
  float* as_   = (float*)alloc((size_t)N_NODES * 4 * 4);
  float* ad_   = (float*)alloc((size_t)N_NODES * 4 * 4);

  hipMemsetAsync(d_ws, 0, zero_bytes, stream);

  build_edges_kernel<<<(EN + 255) / 256, 256, 0, stream>>>(ei, src32, dst32, deg);
  scan_kernel<<<1, 1024, 0, stream>>>(deg, off);
  scatter_kernel<<<(EN + 255) / 256, 256, 0, stream>>>(src32, dst32, off, cursor, csrc);

  const float* in_ptr = x;
  for (int L = 0; L < 3; ++L) {
    gemm128_kernel<<<dim3((N_NODES + 63) / 64, DH / 64), 256, 0, stream>>>(
        in_ptr, W[L], H16, N_NODES, DH);
    alpha_kernel<<<N_NODES, 256, 0, stream>>>(H16, asrc[L], adst[L], as_, ad_);
    softmax_kernel<<<N_NODES / 4, 256, 0, stream>>>(as_, ad_, off, csrc, alpha);
    float* outp = (L == 2) ? (float*)d_out : Ob;
    agg_kernel<<<N_NODES, 256, 0, stream>>>(H16, alpha, off, csrc, bias[L], outp);
    if (L < 2) {
      float* st = (L == 0) ? stats0 : stats1;
      bn_stats_kernel<<<64, 256, 0, stream>>>(Ob, st);
      bn_apply_kernel<<<(N_NODES * DIM + 255) / 256, 256, 0, stream>>>(
          Ob, st, gamma[L], beta[L]);
      in_ptr = Ob;
    }
  }

  // edge_attr passthrough (second tuple element)
  hipMemcpyAsync((float*)d_out + (size_t)N_NODES * DIM, eattr,
                 (size_t)N_EDGES * 16 * 4, hipMemcpyDeviceToDevice, stream);
}

// Round 4
// 536.354 us; speedup vs baseline: 1.4242x; 1.1733x over previous
//
#include <hip/hip_runtime.h>
#include <hip/hip_fp16.h>
#include <math.h>

#define N_NODES 20000
#define N_EDGES 320000
#define EN (N_EDGES + N_NODES)   // edges + self loops = 340000
#define DIM 128
#define HEADS 4
#define DH (HEADS * DIM)         // 512
#define NEG_SLOPE 0.2f
#define BN_EPS 1e-5f

typedef _Float16 h4 __attribute__((ext_vector_type(4)));
typedef _Float16 h8 __attribute__((ext_vector_type(8)));
typedef float f4 __attribute__((ext_vector_type(4)));

__device__ __forceinline__ float lrelu(float x) { return x > 0.f ? x : NEG_SLOPE * x; }

// ---------------- graph build ----------------

__global__ __launch_bounds__(256) void build_edges_kernel(
    const void* __restrict__ ei_raw, int* __restrict__ src32,
    int* __restrict__ dst32, int* __restrict__ deg) {
  int e = blockIdx.x * 256 + threadIdx.x;
  if (e >= EN) return;
  const long long* ei64 = (const long long*)ei_raw;
  const int* ei32 = (const int*)ei_raw;
  bool is64 = true;
#pragma unroll
  for (int k = 0; k < 4; ++k) {
    long long v = ei64[k];
    if (v < 0 || v >= N_NODES) is64 = false;
  }
  int s, d;
  if (e < N_EDGES) {
    if (is64) { s = (int)ei64[e]; d = (int)ei64[N_EDGES + e]; }
    else      { s = ei32[e];      d = ei32[N_EDGES + e]; }
  } else {
    s = d = e - N_EDGES;  // self loop
  }
  src32[e] = s;
  dst32[e] = d;
  atomicAdd(&deg[d], 1);
}

__global__ __launch_bounds__(1024) void scan_kernel(
    const int* __restrict__ deg, int* __restrict__ off) {
  __shared__ int sums[1024];
  const int tid = threadIdx.x;
  const int chunk = (N_NODES + 1023) / 1024;  // 20
  int start = tid * chunk;
  int end = start + chunk; if (end > N_NODES) end = N_NODES;
  int s = 0;
  for (int i = start; i < end && i < N_NODES; ++i) s += deg[i];
  sums[tid] = s;
  __syncthreads();
  for (int st = 1; st < 1024; st <<= 1) {
    int t = (tid >= st) ? sums[tid - st] : 0;
    __syncthreads();
    sums[tid] += t;
    __syncthreads();
  }
  int run = sums[tid] - s;  // exclusive prefix of this thread's chunk
  for (int i = start; i < end && i < N_NODES; ++i) { off[i] = run; run += deg[i]; }
  if (tid == 1023) off[N_NODES] = sums[1023];
}

__global__ __launch_bounds__(256) void scatter_kernel(
    const int* __restrict__ src32, const int* __restrict__ dst32,
    const int* __restrict__ off, int* __restrict__ cursor,
    int* __restrict__ csrc) {
  int e = blockIdx.x * 256 + threadIdx.x;
  if (e >= EN) return;
  int d = dst32[e];
  int pos = atomicAdd(&cursor[d], 1);
  csrc[off[d] + pos] = src32[e];
}

// ---------------- W transpose: [128 k][512 n] fp32 -> [512 n][128 k] fp16 ----

__global__ __launch_bounds__(128) void wtrans_kernel(
    const float* __restrict__ W, __half* __restrict__ Wt) {
  int n = blockIdx.x;     // 512 blocks
  int k = threadIdx.x;    // 128 threads
  Wt[(size_t)n * 128 + k] = __float2half(W[(size_t)k * 512 + n]);
}

// ---------------- MFMA GEMM: [M x 128] fp32 @ Wt[512 x 128] fp16 -> H fp16 ----
// A-operand = W rows (n), B-operand = X rows as cols (m).
// D: col=lane&15 -> m, row=(lane>>4)*4+i -> n  [m89-verified C/D layout]

#define SWZ(r, byte_in_row) (((r) * 256 + (byte_in_row)) ^ (((r) & 7) << 4))

__global__ __launch_bounds__(256) void gemm_mfma_kernel(
    const float* __restrict__ A, const __half* __restrict__ Wt,
    ushort* __restrict__ H16, int M) {
  __shared__ __align__(16) char Xt[64 * 256];  // 64 m-rows x 128 k fp16, swizzled
  __shared__ __align__(16) char Wl[64 * 256];  // 64 n-rows x 128 k fp16, swizzled
  int tid = threadIdx.x;
  int brow = blockIdx.x * 64;  // m base
  int bn = blockIdx.y * 64;    // n base
  // stage X: fp32 -> fp16, swizzled
#pragma unroll
  for (int it = 0; it < 8; ++it) {
    int idx = it * 256 + tid;
    int r = idx >> 5, c4 = idx & 31;  // k = c4*4
    int row = brow + r;
    float4 v = make_float4(0.f, 0.f, 0.f, 0.f);
    if (row < M) v = *(const float4*)&A[(size_t)row * 128 + c4 * 4];
    h4 hv;
    hv[0] = (_Float16)v.x; hv[1] = (_Float16)v.y;
    hv[2] = (_Float16)v.z; hv[3] = (_Float16)v.w;
    *(h4*)(Xt + SWZ(r, c4 * 8)) = hv;
  }
  // stage W tile (already fp16): 16B loads, swizzled
#pragma unroll
  for (int it = 0; it < 4; ++it) {
    int idx = it * 256 + tid;
    int r = idx >> 4, c4 = idx & 15;  // k = c4*8
    uint4 v = *(const uint4*)&Wt[(size_t)(bn + r) * 128 + c4 * 8];
    *(uint4*)(Wl + SWZ(r, c4 * 16)) = v;
  }
  __syncthreads();
  int wave = tid >> 6, lane = tid & 63;
  int lrow = lane & 15, kgrp = lane >> 4;
  f4 acc[4] = {};
#pragma unroll
  for (int ks = 0; ks < 4; ++ks) {
    int kb = ks * 64 + kgrp * 16;  // byte offset of this lane's 8 halves
    int wr = wave * 16 + lrow;
    h8 af = *(h8*)(Wl + SWZ(wr, kb));
#pragma unroll
    for (int mt = 0; mt < 4; ++mt) {
      int xr = mt * 16 + lrow;
      h8 bf = *(h8*)(Xt + SWZ(xr, kb));
      acc[mt] = __builtin_amdgcn_mfma_f32_16x16x32_f16(af, bf, acc[mt], 0, 0, 0);
    }
  }
  // epilogue: lane holds m = mt*16 + (lane&15), n = wave*16 + kgrp*4 + i
#pragma unroll
  for (int mt = 0; mt < 4; ++mt) {
    int m = brow + mt * 16 + lrow;
    if (m < M) {
      h4 hv;
#pragma unroll
      for (int i = 0; i < 4; ++i) hv[i] = (_Float16)acc[mt][i];
      *(h4*)&H16[(size_t)m * DH + bn + wave * 16 + kgrp * 4] = hv;
    }
  }
}

// ---------------- attention coefficients ----------------

// one block per node; wave w (of 4) handles head w; 64 lanes x half2 = 128 ch
__global__ __launch_bounds__(256) void alpha_kernel(
    const ushort* __restrict__ H16, const float* __restrict__ a_src,
    const float* __restrict__ a_dst, float* __restrict__ as_,
    float* __restrict__ ad_) {
  int n = blockIdx.x;
  int head = threadIdx.x >> 6;
  int lane = threadIdx.x & 63;
  const __half2* hp = (const __half2*)(H16 + (size_t)n * DH) + head * 64 + lane;
  float2 h = __half22float2(*hp);
  float s = h.x * a_src[head * DIM + 2 * lane] + h.y * a_src[head * DIM + 2 * lane + 1];
  float d = h.x * a_dst[head * DIM + 2 * lane] + h.y * a_dst[head * DIM + 2 * lane + 1];
#pragma unroll
  for (int o = 32; o > 0; o >>= 1) {
    s += __shfl_xor(s, o);
    d += __shfl_xor(d, o);
  }
  if (lane == 0) {
    as_[n * 4 + head] = s;
    ad_[n * 4 + head] = d;
  }
}

// ---------------- fused segment-softmax + aggregation ----------------
// block = 256 thr = 2 nodes x 2 waves. Per node: wave 0 computes softmax
// (deg<=64 register path -> LDS; generic path -> global fallback), then both
// waves aggregate with 8B H loads (wave wv covers heads 2wv..2wv+1).

__global__ __launch_bounds__(256) void smagg_kernel(
    const ushort* __restrict__ H16, const float* __restrict__ as_,
    const float* __restrict__ ad_, const int* __restrict__ off,
    const int* __restrict__ csrc, const float* __restrict__ bias,
    float* __restrict__ out, float* __restrict__ galpha) {
  __shared__ float4 alds[2][64];
  __shared__ float4 xred[2][32];
  int tid = threadIdx.x;
  int half = tid >> 7;          // node within block
  int n = blockIdx.x * 2 + half;
  int wv = (tid >> 6) & 1;      // wave within node
  int lane = tid & 63;
  int e0 = off[n], e1 = off[n + 1];
  int deg = e1 - e0;
  bool fast = (deg <= 64);
  if (wv == 0) {
    float4 ad = *(const float4*)&ad_[n * 4];
    if (fast) {
      int i = e0 + lane;
      bool valid = lane < deg;
      float l0 = -1e30f, l1 = -1e30f, l2 = -1e30f, l3 = -1e30f;
      if (valid) {
        int s = csrc[i];
        float4 av = *(const float4*)&as_[s * 4];
        l0 = lrelu(av.x + ad.x); l1 = lrelu(av.y + ad.y);
        l2 = lrelu(av.z + ad.z); l3 = lrelu(av.w + ad.w);
      }
      float m0 = l0, m1 = l1, m2 = l2, m3 = l3;
#pragma unroll
      for (int o = 32; o > 0; o >>= 1) {
        m0 = fmaxf(m0, __shfl_xor(m0, o)); m1 = fmaxf(m1, __shfl_xor(m1, o));
        m2 = fmaxf(m2, __shfl_xor(m2, o)); m3 = fmaxf(m3, __shfl_xor(m3, o));
      }
      float p0 = valid ? expf(l0 - m0) : 0.f;
      float p1 = valid ? expf(l1 - m1) : 0.f;
      float p2 = valid ? expf(l2 - m2) : 0.f;
      float p3 = valid ? expf(l3 - m3) : 0.f;
      float z0 = p0, z1 = p1, z2 = p2, z3 = p3;
#pragma unroll
      for (int o = 32; o > 0; o >>= 1) {
        z0 += __shfl_xor(z0, o); z1 += __shfl_xor(z1, o);
        z2 += __shfl_xor(z2, o); z3 += __shfl_xor(z3, o);
      }
      if (valid) {
        alds[half][lane] = make_float4(p0 / (z0 + 1e-16f), p1 / (z1 + 1e-16f),
                                       p2 / (z2 + 1e-16f), p3 / (z3 + 1e-16f));
      }
    } else {
      // generic path (rare): normalized alpha to global buffer
      float m0 = -1e30f, m1 = -1e30f, m2 = -1e30f, m3 = -1e30f;
      for (int i = e0 + lane; i < e1; i += 64) {
        int s = csrc[i];
        float4 av = *(const float4*)&as_[s * 4];
        float l0 = lrelu(av.x + ad.x), l1 = lrelu(av.y + ad.y);
        float l2 = lrelu(av.z + ad.z), l3 = lrelu(av.w + ad.w);
        ((float4*)galpha)[i] = make_float4(l0, l1, l2, l3);
        m0 = fmaxf(m0, l0); m1 = fmaxf(m1, l1);
        m2 = fmaxf(m2, l2); m3 = fmaxf(m3, l3);
      }
#pragma unroll
      for (int o = 32; o > 0; o >>= 1) {
        m0 = fmaxf(m0, __shfl_xor(m0, o)); m1 = fmaxf(m1, __shfl_xor(m1, o));
        m2 = fmaxf(m2, __shfl_xor(m2, o)); m3 = fmaxf(m3, __shfl_xor(m3, o));
      }
      float z0 = 0.f, z1 = 0.f, z2 = 0.f, z3 = 0.f;
      for (int i = e0 + lane; i < e1; i += 64) {
        float4 l = ((const float4*)galpha)[i];
        float p0 = expf(l.x - m0), p1 = expf(l.y - m1);
        float p2 = expf(l.z - m2), p3 = expf(l.w - m3);
        ((float4*)galpha)[i] = make_float4(p0, p1, p2, p3);
        z0 += p0; z1 += p1; z2 += p2; z3 += p3;
      }
#pragma unroll
      for (int o = 32; o > 0; o >>= 1) {
        z0 += __shfl_xor(z0, o); z1 += __shfl_xor(z1, o);
        z2 += __shfl_xor(z2, o); z3 += __shfl_xor(z3, o);
      }
      float r0 = 1.f / (z0 + 1e-16f), r1 = 1.f / (z1 + 1e-16f);
      float r2 = 1.f / (z2 + 1e-16f), r3 = 1.f / (z3 + 1e-16f);
      for (int i = e0 + lane; i < e1; i += 64) {
        float4 p = ((const float4*)galpha)[i];
        ((float4*)galpha)[i] = make_float4(p.x * r0, p.y * r1, p.z * r2, p.w * r3);
      }
    }
  }
  __syncthreads();
  // aggregation: lane covers 4 channels of head hh = wv*2 + (lane>>5)
  const uint2* Hp = (const uint2*)H16;  // 8B units; node row = 128 units
  const float* alds_f = (const float*)&alds[half][0];
  int hh = wv * 2 + (lane >> 5);
  float a0 = 0.f, a1 = 0.f, a2 = 0.f, a3 = 0.f;
  int i = e0;
#define AGG_BODY(ii)                                                          \
  {                                                                           \
    int s = csrc[ii];                                                         \
    float w = fast ? alds_f[((ii) - e0) * 4 + hh] : galpha[(size_t)(ii) * 4 + hh]; \
    uint2 hvv = Hp[(size_t)s * 128 + wv * 64 + lane];                         \
    float2 lo = __half22float2(*(__half2*)&hvv.x);                            \
    float2 hi = __half22float2(*(__half2*)&hvv.y);                            \
    a0 += w * lo.x; a1 += w * lo.y; a2 += w * hi.x; a3 += w * hi.y;           \
  }
  for (; i + 3 < e1; i += 4) { AGG_BODY(i) AGG_BODY(i + 1) AGG_BODY(i + 2) AGG_BODY(i + 3) }
  for (; i < e1; ++i) AGG_BODY(i)
#undef AGG_BODY
  // head-pair reduce within wave: lane l and l^32 hold same channels
  a0 += __shfl_xor(a0, 32); a1 += __shfl_xor(a1, 32);
  a2 += __shfl_xor(a2, 32); a3 += __shfl_xor(a3, 32);
  if (wv == 1 && lane < 32) xred[half][lane] = make_float4(a0, a1, a2, a3);
  __syncthreads();
  if (wv == 0 && lane < 32) {
    float4 o2 = xred[half][lane];
    float4 bv = *(const float4*)&bias[lane * 4];
    float4 r;
    r.x = 0.25f * (a0 + o2.x) + bv.x;
    r.y = 0.25f * (a1 + o2.y) + bv.y;
    r.z = 0.25f * (a2 + o2.z) + bv.z;
    r.w = 0.25f * (a3 + o2.w) + bv.w;
    *(float4*)&out[(size_t)n * DIM + lane * 4] = r;
  }
}

// ---------------- batchnorm ----------------

__global__ __launch_bounds__(256) void bn_stats_kernel(
    const float* __restrict__ X, float* __restrict__ stats) {
  int c = threadIdx.x & 127;
  int half = threadIdx.x >> 7;
  float s = 0.f, s2 = 0.f;
  for (int r = blockIdx.x * 2 + half; r < N_NODES; r += gridDim.x * 2) {
    float v = X[(size_t)r * DIM + c];
    s += v;
    s2 += v * v;
  }
  atomicAdd(&stats[c], s);
  atomicAdd(&stats[DIM + c], s2);
}

__global__ __launch_bounds__(256) void bn_apply_kernel(
    float* __restrict__ X, const float* __restrict__ stats,
    const float* __restrict__ gamma, const float* __restrict__ beta) {
  int idx = blockIdx.x * 256 + threadIdx.x;
  if (idx >= N_NODES * DIM) return;
  int c = idx & 127;
  const float invN = 1.f / (float)N_NODES;
  float mean = stats[c] * invN;
  float var = stats[DIM + c] * invN - mean * mean;
  float scale = gamma[c] * rsqrtf(var + BN_EPS);
  float shift = beta[c] - mean * scale;
  float v = X[idx] * scale + shift;
  X[idx] = fmaxf(v, 0.f);
}

// ---------------- launch ----------------

extern "C" void kernel_launch(void* const* d_in, const int* in_sizes, int n_in,
                              void* d_out, int out_size, void* d_ws, size_t ws_size,
                              hipStream_t stream) {
  (void)in_sizes; (void)n_in; (void)out_size; (void)ws_size;
  const float* x = (const float*)d_in[0];
  const void* ei = d_in[1];
  const float* eattr = (const float*)d_in[2];
  const float* W[3]    = {(const float*)d_in[3],  (const float*)d_in[7],  (const float*)d_in[11]};
  const float* asrc[3] = {(const float*)d_in[4],  (const float*)d_in[8],  (const float*)d_in[12]};
  const float* adst[3] = {(const float*)d_in[5],  (const float*)d_in[9],  (const float*)d_in[13]};
  const float* bias[3] = {(const float*)d_in[6],  (const float*)d_in[10], (const float*)d_in[14]};
  const float* gamma[2] = {(const float*)d_in[15], (const float*)d_in[17]};
  const float* beta[2]  = {(const float*)d_in[16], (const float*)d_in[18]};

  char* ws = (char*)d_ws;
  size_t o = 0;
  auto alloc = [&](size_t bytes) -> void* {
    void* p = ws + o;
    o += (bytes + 255) & ~(size_t)255;
    return p;
  };
  // zero-init region first (deg, cursor, bn stats)
  int* deg      = (int*)alloc(N_NODES * 4);
  int* cursor   = (int*)alloc(N_NODES * 4);
  float* stats0 = (float*)alloc(2 * DIM * 4);
  float* stats1 = (float*)alloc(2 * DIM * 4);
  size_t zero_bytes = o;
  int* off    = (int*)alloc((N_NODES + 1) * 4);
  int* src32  = (int*)alloc((size_t)EN * 4);
  int* dst32  = (int*)alloc((size_t)EN * 4);
  int* csrc   = (int*)alloc((size_t)EN * 4);
  float* galpha = (float*)alloc((size_t)EN * 4 * 4);
  ushort* H16  = (ushort*)alloc((size_t)N_NODES * DH * 2);
  float* Ob    = (float*)alloc((size_t)N_NODES * DIM * 4);
  float* as_   = (float*)alloc((size_t)N_NODES * 4 * 4);
  float* ad_   = (float*)alloc((size_t)N_NODES * 4 * 4);
  __half* Wt[3];
  for (int L = 0; L < 3; ++L) Wt[L] = (__half*)alloc((size_t)DH * 128 * 2);

  hipMemsetAsync(d_ws, 0, zero_bytes, stream);

  build_edges_kernel<<<(EN + 255) / 256, 256, 0, stream>>>(ei, src32, dst32, deg);
  scan_kernel<<<1, 1024, 0, stream>>>(deg, off);
  scatter_kernel<<<(EN + 255) / 256, 256, 0, stream>>>(src32, dst32, off, cursor, csrc);
  for (int L = 0; L < 3; ++L)
    wtrans_kernel<<<DH, 128, 0, stream>>>(W[L], Wt[L]);

  const float* in_ptr = x;
  for (int L = 0; L < 3; ++L) {
    gemm_mfma_kernel<<<dim3((N_NODES + 63) / 64, DH / 64), 256, 0, stream>>>(
        in_ptr, Wt[L], H16, N_NODES);
    alpha_kernel<<<N_NODES, 256, 0, stream>>>(H16, asrc[L], adst[L], as_, ad_);
    float* outp = (L == 2) ? (float*)d_out : Ob;
    smagg_kernel<<<N_NODES / 2, 256, 0, stream>>>(H16, as_, ad_, off, csrc,
                                                  bias[L], outp, galpha);
    if (L < 2) {
      float* st = (L == 0) ? stats0 : stats1;
      bn_stats_kernel<<<256, 256, 0, stream>>>(Ob, st);
      bn_apply_kernel<<<(N_NODES * DIM + 255) / 256, 256, 0, stream>>>(
          Ob, st, gamma[L], beta[L]);
      in_ptr = Ob;
    }
  }

  // edge_attr passthrough (second tuple element)
  hipMemcpyAsync((float*)d_out + (size_t)N_NODES * DIM, eattr,
                 (size_t)N_EDGES * 16 * 4, hipMemcpyDeviceToDevice, stream);
}

// Round 5
// 444.621 us; speedup vs baseline: 1.7181x; 1.2063x over previous
//
#include <hip/hip_runtime.h>
#include <hip/hip_fp16.h>
#include <math.h>

#define N_NODES 20000
#define N_EDGES 320000
#define EN (N_EDGES + N_NODES)   // edges + self loops = 340000
#define DIM 128
#define HEADS 4
#define DH (HEADS * DIM)         // 512
#define NEG_SLOPE 0.2f
#define BN_EPS 1e-5f

typedef _Float16 h4 __attribute__((ext_vector_type(4)));
typedef _Float16 h8 __attribute__((ext_vector_type(8)));
typedef float f4 __attribute__((ext_vector_type(4)));

__device__ __forceinline__ float lrelu(float x) { return x > 0.f ? x : NEG_SLOPE * x; }

// ---------------- graph build ----------------

__global__ __launch_bounds__(256) void build_edges_kernel(
    const void* __restrict__ ei_raw, int* __restrict__ src32,
    int* __restrict__ dst32, int* __restrict__ deg) {
  int e = blockIdx.x * 256 + threadIdx.x;
  if (e >= EN) return;
  const long long* ei64 = (const long long*)ei_raw;
  const int* ei32 = (const int*)ei_raw;
  bool is64 = true;
#pragma unroll
  for (int k = 0; k < 4; ++k) {
    long long v = ei64[k];
    if (v < 0 || v >= N_NODES) is64 = false;
  }
  int s, d;
  if (e < N_EDGES) {
    if (is64) { s = (int)ei64[e]; d = (int)ei64[N_EDGES + e]; }
    else      { s = ei32[e];      d = ei32[N_EDGES + e]; }
  } else {
    s = d = e - N_EDGES;  // self loop
  }
  src32[e] = s;
  dst32[e] = d;
  atomicAdd(&deg[d], 1);
}

__global__ __launch_bounds__(1024) void scan_kernel(
    const int* __restrict__ deg, int* __restrict__ off) {
  __shared__ int sums[1024];
  const int tid = threadIdx.x;
  const int chunk = (N_NODES + 1023) / 1024;  // 20
  int start = tid * chunk;
  int end = start + chunk; if (end > N_NODES) end = N_NODES;
  int s = 0;
  for (int i = start; i < end && i < N_NODES; ++i) s += deg[i];
  sums[tid] = s;
  __syncthreads();
  for (int st = 1; st < 1024; st <<= 1) {
    int t = (tid >= st) ? sums[tid - st] : 0;
    __syncthreads();
    sums[tid] += t;
    __syncthreads();
  }
  int run = sums[tid] - s;  // exclusive prefix of this thread's chunk
  for (int i = start; i < end && i < N_NODES; ++i) { off[i] = run; run += deg[i]; }
  if (tid == 1023) off[N_NODES] = sums[1023];
}

__global__ __launch_bounds__(256) void scatter_kernel(
    const int* __restrict__ src32, const int* __restrict__ dst32,
    const int* __restrict__ off, int* __restrict__ cursor,
    int* __restrict__ csrc) {
  int e = blockIdx.x * 256 + threadIdx.x;
  if (e >= EN) return;
  int d = dst32[e];
  int pos = atomicAdd(&cursor[d], 1);
  csrc[off[d] + pos] = src32[e];
}

// ---------------- W transpose (all 3 layers): [128 k][512 n] -> [512 n][128 k] fp16

__global__ __launch_bounds__(128) void wtrans_kernel(
    const float* __restrict__ W0, const float* __restrict__ W1,
    const float* __restrict__ W2, __half* __restrict__ T0,
    __half* __restrict__ T1, __half* __restrict__ T2) {
  int n = blockIdx.x;     // 512
  int k = threadIdx.x;    // 128
  const float* W = (blockIdx.y == 0) ? W0 : (blockIdx.y == 1) ? W1 : W2;
  __half* T = (blockIdx.y == 0) ? T0 : (blockIdx.y == 1) ? T1 : T2;
  T[(size_t)n * 128 + k] = __float2half(W[(size_t)k * 512 + n]);
}

// ---------------- BN coefficients ----------------

__global__ __launch_bounds__(128) void bn_coef_kernel(
    const float* __restrict__ stats, const float* __restrict__ gamma,
    const float* __restrict__ beta, float* __restrict__ coef) {
  int c = threadIdx.x;
  const float invN = 1.f / (float)N_NODES;
  float mean = stats[c] * invN;
  float var = stats[DIM + c] * invN - mean * mean;
  float scale = gamma[c] * rsqrtf(var + BN_EPS);
  coef[c] = scale;
  coef[DIM + c] = beta[c] - mean * scale;
}

// ---------------- fused GEMM + BN(optional) + alpha dots ----------------
// Block: 64 m-rows x 256 n-cols (half = blockIdx.y selects heads 2*half..2*half+1).
// A-op = W rows (n), B-op = X rows (m).
// D: col=lane&15 -> m, row=(lane>>4)*4+i -> n  [m89-verified C/D layout]

#define SWZ(r, byte_in_row) (((r) * 256 + (byte_in_row)) ^ (((r) & 7) << 4))

__global__ __launch_bounds__(256) void gemm_fused_kernel(
    const float* __restrict__ A, const __half* __restrict__ Wt,
    const float* __restrict__ coef, int apply_bn,
    const float* __restrict__ a_src, const float* __restrict__ a_dst,
    ushort* __restrict__ H16, float* __restrict__ as_,
    float* __restrict__ ad_, int M) {
  __shared__ __align__(16) char Xt[64 * 256];  // 64 m x 128 k fp16, swizzled
  __shared__ __align__(16) char Wl[64 * 256];  // 64 n x 128 k fp16, swizzled
  __shared__ float red_as[4][4][2][16];        // [wave][mt][hh][lrow]
  __shared__ float red_ad[4][4][2][16];
  int tid = threadIdx.x;
  int brow = blockIdx.x * 64;
  int half_id = blockIdx.y;          // 0: heads 0-1 (n 0..255), 1: heads 2-3
  const float4* coef4 = (const float4*)coef;
  // stage X (fp32 -> fp16, optional BN+ReLU, swizzled)
#pragma unroll
  for (int it = 0; it < 8; ++it) {
    int idx = it * 256 + tid;
    int r = idx >> 5, c4 = idx & 31;  // k = c4*4
    int row = brow + r;
    float4 v = make_float4(0.f, 0.f, 0.f, 0.f);
    if (row < M) {
      v = *(const float4*)&A[(size_t)row * 128 + c4 * 4];
      if (apply_bn) {
        float4 sc = coef4[c4], sh = coef4[32 + c4];
        v.x = fmaxf(v.x * sc.x + sh.x, 0.f);
        v.y = fmaxf(v.y * sc.y + sh.y, 0.f);
        v.z = fmaxf(v.z * sc.z + sh.z, 0.f);
        v.w = fmaxf(v.w * sc.w + sh.w, 0.f);
      }
    }
    h4 hv;
    hv[0] = (_Float16)v.x; hv[1] = (_Float16)v.y;
    hv[2] = (_Float16)v.z; hv[3] = (_Float16)v.w;
    *(h4*)(Xt + SWZ(r, c4 * 8)) = hv;
  }
  int wave = tid >> 6, lane = tid & 63;
  int lrow = lane & 15, kgrp = lane >> 4;
  float asum[4][2] = {}, adsum[4][2] = {};
  for (int nc = 0; nc < 4; ++nc) {
    int chunk = half_id * 4 + nc;    // global n-chunk 0..7
    int hh = nc >> 1;                // head within half
    __syncthreads();                 // protect Wl from previous chunk readers
#pragma unroll
    for (int it = 0; it < 4; ++it) {
      int idx = it * 256 + tid;
      int r = idx >> 4, c4 = idx & 15;
      uint4 v = *(const uint4*)&Wt[(size_t)(chunk * 64 + r) * 128 + c4 * 8];
      *(uint4*)(Wl + SWZ(r, c4 * 16)) = v;
    }
    __syncthreads();
    f4 acc[4] = {};
#pragma unroll
    for (int ks = 0; ks < 4; ++ks) {
      int kb = ks * 64 + kgrp * 16;
      h8 af = *(h8*)(Wl + SWZ(wave * 16 + lrow, kb));
#pragma unroll
      for (int mt = 0; mt < 4; ++mt) {
        h8 bf = *(h8*)(Xt + SWZ(mt * 16 + lrow, kb));
        acc[mt] = __builtin_amdgcn_mfma_f32_16x16x32_f16(af, bf, acc[mt], 0, 0, 0);
      }
    }
    int n_base = chunk * 64 + wave * 16 + kgrp * 4;
    float4 as4 = *(const float4*)&a_src[n_base];
    float4 ad4 = *(const float4*)&a_dst[n_base];
#pragma unroll
    for (int mt = 0; mt < 4; ++mt) {
      int m = brow + mt * 16 + lrow;
      if (m < M) {
        h4 hv;
#pragma unroll
        for (int i = 0; i < 4; ++i) hv[i] = (_Float16)acc[mt][i];
        *(h4*)&H16[(size_t)m * DH + n_base] = hv;
      }
      asum[mt][hh] += acc[mt][0] * as4.x + acc[mt][1] * as4.y +
                      acc[mt][2] * as4.z + acc[mt][3] * as4.w;
      adsum[mt][hh] += acc[mt][0] * ad4.x + acc[mt][1] * ad4.y +
                       acc[mt][2] * ad4.z + acc[mt][3] * ad4.w;
    }
  }
  // reduce over kgrp within wave
#pragma unroll
  for (int mt = 0; mt < 4; ++mt)
#pragma unroll
    for (int hh = 0; hh < 2; ++hh) {
      asum[mt][hh] += __shfl_xor(asum[mt][hh], 16);
      asum[mt][hh] += __shfl_xor(asum[mt][hh], 32);
      adsum[mt][hh] += __shfl_xor(adsum[mt][hh], 16);
      adsum[mt][hh] += __shfl_xor(adsum[mt][hh], 32);
    }
  __syncthreads();
  if (lane < 16) {
#pragma unroll
    for (int mt = 0; mt < 4; ++mt)
#pragma unroll
      for (int hh = 0; hh < 2; ++hh) {
        red_as[wave][mt][hh][lrow] = asum[mt][hh];
        red_ad[wave][mt][hh][lrow] = adsum[mt][hh];
      }
  }
  __syncthreads();
  if (tid < 128) {
    int mt = tid >> 5, hh = (tid >> 4) & 1, lr = tid & 15;
    float s = red_as[0][mt][hh][lr] + red_as[1][mt][hh][lr] +
              red_as[2][mt][hh][lr] + red_as[3][mt][hh][lr];
    float d = red_ad[0][mt][hh][lr] + red_ad[1][mt][hh][lr] +
              red_ad[2][mt][hh][lr] + red_ad[3][mt][hh][lr];
    int m = brow + mt * 16 + lr;
    if (m < M) {
      int head = half_id * 2 + hh;
      as_[m * 4 + head] = s;
      ad_[m * 4 + head] = d;
    }
  }
}

// ---------------- fused segment-softmax + aggregation ----------------
// 256 thr = 4 waves = 4 nodes. Each wave: softmax (deg<=64 register path ->
// LDS; generic -> global fallback), then aggregates with 16B/lane loads,
// 8-deep unroll. lane covers head=lane>>4, channels (lane&15)*8..+7.

__global__ __launch_bounds__(256) void smagg_kernel(
    const ushort* __restrict__ H16, const float* __restrict__ as_,
    const float* __restrict__ ad_, const int* __restrict__ off,
    const int* __restrict__ csrc, const float* __restrict__ bias,
    float* __restrict__ out, float* __restrict__ galpha) {
  __shared__ float alds[4][64 * 4];
  int tid = threadIdx.x;
  int slot = tid >> 6;
  int n = blockIdx.x * 4 + slot;
  int lane = tid & 63;
  int e0 = off[n], e1 = off[n + 1];
  int deg = e1 - e0;
  bool fast = (deg <= 64);
  float4 ad = *(const float4*)&ad_[n * 4];
  if (fast) {
    bool valid = lane < deg;
    float l0 = -1e30f, l1 = -1e30f, l2 = -1e30f, l3 = -1e30f;
    if (valid) {
      int s = csrc[e0 + lane];
      float4 av = *(const float4*)&as_[s * 4];
      l0 = lrelu(av.x + ad.x); l1 = lrelu(av.y + ad.y);
      l2 = lrelu(av.z + ad.z); l3 = lrelu(av.w + ad.w);
    }
    float m0 = l0, m1 = l1, m2 = l2, m3 = l3;
#pragma unroll
    for (int o = 32; o > 0; o >>= 1) {
      m0 = fmaxf(m0, __shfl_xor(m0, o)); m1 = fmaxf(m1, __shfl_xor(m1, o));
      m2 = fmaxf(m2, __shfl_xor(m2, o)); m3 = fmaxf(m3, __shfl_xor(m3, o));
    }
    float p0 = valid ? expf(l0 - m0) : 0.f;
    float p1 = valid ? expf(l1 - m1) : 0.f;
    float p2 = valid ? expf(l2 - m2) : 0.f;
    float p3 = valid ? expf(l3 - m3) : 0.f;
    float z0 = p0, z1 = p1, z2 = p2, z3 = p3;
#pragma unroll
    for (int o = 32; o > 0; o >>= 1) {
      z0 += __shfl_xor(z0, o); z1 += __shfl_xor(z1, o);
      z2 += __shfl_xor(z2, o); z3 += __shfl_xor(z3, o);
    }
    if (valid) {
      float4 r = make_float4(p0 / (z0 + 1e-16f), p1 / (z1 + 1e-16f),
                             p2 / (z2 + 1e-16f), p3 / (z3 + 1e-16f));
      *(float4*)&alds[slot][lane * 4] = r;
    }
  } else {
    // generic path (rare): normalized alpha to global buffer
    float m0 = -1e30f, m1 = -1e30f, m2 = -1e30f, m3 = -1e30f;
    for (int i = e0 + lane; i < e1; i += 64) {
      int s = csrc[i];
      float4 av = *(const float4*)&as_[s * 4];
      float l0 = lrelu(av.x + ad.x), l1 = lrelu(av.y + ad.y);
      float l2 = lrelu(av.z + ad.z), l3 = lrelu(av.w + ad.w);
      ((float4*)galpha)[i] = make_float4(l0, l1, l2, l3);
      m0 = fmaxf(m0, l0); m1 = fmaxf(m1, l1);
      m2 = fmaxf(m2, l2); m3 = fmaxf(m3, l3);
    }
#pragma unroll
    for (int o = 32; o > 0; o >>= 1) {
      m0 = fmaxf(m0, __shfl_xor(m0, o)); m1 = fmaxf(m1, __shfl_xor(m1, o));
      m2 = fmaxf(m2, __shfl_xor(m2, o)); m3 = fmaxf(m3, __shfl_xor(m3, o));
    }
    float z0 = 0.f, z1 = 0.f, z2 = 0.f, z3 = 0.f;
    for (int i = e0 + lane; i < e1; i += 64) {
      float4 l = ((const float4*)galpha)[i];
      float p0 = expf(l.x - m0), p1 = expf(l.y - m1);
      float p2 = expf(l.z - m2), p3 = expf(l.w - m3);
      ((float4*)galpha)[i] = make_float4(p0, p1, p2, p3);
      z0 += p0; z1 += p1; z2 += p2; z3 += p3;
    }
#pragma unroll
    for (int o = 32; o > 0; o >>= 1) {
      z0 += __shfl_xor(z0, o); z1 += __shfl_xor(z1, o);
      z2 += __shfl_xor(z2, o); z3 += __shfl_xor(z3, o);
    }
    float r0 = 1.f / (z0 + 1e-16f), r1 = 1.f / (z1 + 1e-16f);
    float r2 = 1.f / (z2 + 1e-16f), r3 = 1.f / (z3 + 1e-16f);
    for (int i = e0 + lane; i < e1; i += 64) {
      float4 p = ((const float4*)galpha)[i];
      ((float4*)galpha)[i] = make_float4(p.x * r0, p.y * r1, p.z * r2, p.w * r3);
    }
  }
  // aggregation (wave-local; LDS produced by same wave)
  const uint4* Hp = (const uint4*)H16;  // 64 x 16B per node row
  const float* af = &alds[slot][0];
  int head = lane >> 4;
  float acc[8] = {};
#define AGG_BODY(ii)                                                       \
  {                                                                        \
    int s = csrc[ii];                                                      \
    float w = fast ? af[((ii) - e0) * 4 + head]                            \
                   : galpha[(size_t)(ii) * 4 + head];                      \
    uint4 hv = Hp[(size_t)s * 64 + lane];                                  \
    float2 f0 = __half22float2(*(__half2*)&hv.x);                          \
    float2 f1 = __half22float2(*(__half2*)&hv.y);                          \
    float2 f2 = __half22float2(*(__half2*)&hv.z);                          \
    float2 f3 = __half22float2(*(__half2*)&hv.w);                          \
    acc[0] += w * f0.x; acc[1] += w * f0.y;                                \
    acc[2] += w * f1.x; acc[3] += w * f1.y;                                \
    acc[4] += w * f2.x; acc[5] += w * f2.y;                                \
    acc[6] += w * f3.x; acc[7] += w * f3.y;                                \
  }
  int i = e0;
  for (; i + 7 < e1; i += 8) {
    AGG_BODY(i)     AGG_BODY(i + 1) AGG_BODY(i + 2) AGG_BODY(i + 3)
    AGG_BODY(i + 4) AGG_BODY(i + 5) AGG_BODY(i + 6) AGG_BODY(i + 7)
  }
  for (; i < e1; ++i) AGG_BODY(i)
#undef AGG_BODY
  // mean over heads: sum lanes {l, l^16, l^32, l^48}
#pragma unroll
  for (int j = 0; j < 8; ++j) {
    acc[j] += __shfl_xor(acc[j], 16);
    acc[j] += __shfl_xor(acc[j], 32);
  }
  if (lane < 16) {
    int c0 = lane * 8;
    float4 b0 = *(const float4*)&bias[c0];
    float4 b1 = *(const float4*)&bias[c0 + 4];
    float4 r0 = make_float4(0.25f * acc[0] + b0.x, 0.25f * acc[1] + b0.y,
                            0.25f * acc[2] + b0.z, 0.25f * acc[3] + b0.w);
    float4 r1 = make_float4(0.25f * acc[4] + b1.x, 0.25f * acc[5] + b1.y,
                            0.25f * acc[6] + b1.z, 0.25f * acc[7] + b1.w);
    *(float4*)&out[(size_t)n * DIM + c0] = r0;
    *(float4*)&out[(size_t)n * DIM + c0 + 4] = r1;
  }
}

// ---------------- batchnorm stats ----------------

__global__ __launch_bounds__(256) void bn_stats_kernel(
    const float* __restrict__ X, float* __restrict__ stats) {
  int c = threadIdx.x & 127;
  int hlf = threadIdx.x >> 7;
  float s = 0.f, s2 = 0.f;
  for (int r = blockIdx.x * 2 + hlf; r < N_NODES; r += gridDim.x * 2) {
    float v = X[(size_t)r * DIM + c];
    s += v;
    s2 += v * v;
  }
  atomicAdd(&stats[c], s);
  atomicAdd(&stats[DIM + c], s2);
}

// ---------------- launch ----------------

extern "C" void kernel_launch(void* const* d_in, const int* in_sizes, int n_in,
                              void* d_out, int out_size, void* d_ws, size_t ws_size,
                              hipStream_t stream) {
  (void)in_sizes; (void)n_in; (void)out_size; (void)ws_size;
  const float* x = (const float*)d_in[0];
  const void* ei = d_in[1];
  const float* eattr = (const float*)d_in[2];
  const float* W[3]    = {(const float*)d_in[3],  (const float*)d_in[7],  (const float*)d_in[11]};
  const float* asrc[3] = {(const float*)d_in[4],  (const float*)d_in[8],  (const float*)d_in[12]};
  const float* adst[3] = {(const float*)d_in[5],  (const float*)d_in[9],  (const float*)d_in[13]};
  const float* bias[3] = {(const float*)d_in[6],  (const float*)d_in[10], (const float*)d_in[14]};
  const float* gamma[2] = {(const float*)d_in[15], (const float*)d_in[17]};
  const float* beta[2]  = {(const float*)d_in[16], (const float*)d_in[18]};

  char* ws = (char*)d_ws;
  size_t o = 0;
  auto alloc = [&](size_t bytes) -> void* {
    void* p = ws + o;
    o += (bytes + 255) & ~(size_t)255;
    return p;
  };
  // zero-init region first (deg, cursor, bn stats)
  int* deg      = (int*)alloc(N_NODES * 4);
  int* cursor   = (int*)alloc(N_NODES * 4);
  float* stats0 = (float*)alloc(2 * DIM * 4);
  float* stats1 = (float*)alloc(2 * DIM * 4);
  size_t zero_bytes = o;
  int* off    = (int*)alloc((N_NODES + 1) * 4);
  int* src32  = (int*)alloc((size_t)EN * 4);
  int* dst32  = (int*)alloc((size_t)EN * 4);
  int* csrc   = (int*)alloc((size_t)EN * 4);
  float* galpha = (float*)alloc((size_t)EN * 4 * 4);
  ushort* H16  = (ushort*)alloc((size_t)N_NODES * DH * 2);
  float* Ob    = (float*)alloc((size_t)N_NODES * DIM * 4);
  float* as_   = (float*)alloc((size_t)N_NODES * 4 * 4);
  float* ad_   = (float*)alloc((size_t)N_NODES * 4 * 4);
  float* coef0 = (float*)alloc(2 * DIM * 4);
  float* coef1 = (float*)alloc(2 * DIM * 4);
  __half* Wt[3];
  for (int L = 0; L < 3; ++L) Wt[L] = (__half*)alloc((size_t)DH * 128 * 2);

  hipMemsetAsync(d_ws, 0, zero_bytes, stream);

  build_edges_kernel<<<(EN + 255) / 256, 256, 0, stream>>>(ei, src32, dst32, deg);
  scan_kernel<<<1, 1024, 0, stream>>>(deg, off);
  scatter_kernel<<<(EN + 255) / 256, 256, 0, stream>>>(src32, dst32, off, cursor, csrc);
  wtrans_kernel<<<dim3(DH, 3), 128, 0, stream>>>(W[0], W[1], W[2], Wt[0], Wt[1], Wt[2]);

  const float* in_ptr = x;
  const float* coefs[3] = {coef0, coef0, coef1};  // layer 0 unused
  for (int L = 0; L < 3; ++L) {
    gemm_fused_kernel<<<dim3((N_NODES + 63) / 64, 2), 256, 0, stream>>>(
        in_ptr, Wt[L], coefs[L], (L > 0) ? 1 : 0, asrc[L], adst[L],
        H16, as_, ad_, N_NODES);
    float* outp = (L == 2) ? (float*)d_out : Ob;
    smagg_kernel<<<N_NODES / 4, 256, 0, stream>>>(H16, as_, ad_, off, csrc,
                                                  bias[L], outp, galpha);
    if (L < 2) {
      float* st = (L == 0) ? stats0 : stats1;
      float* cf = (L == 0) ? coef0 : coef1;
      bn_stats_kernel<<<256, 256, 0, stream>>>(Ob, st);
      bn_coef_kernel<<<1, 128, 0, stream>>>(st, gamma[L], beta[L], cf);
      in_ptr = Ob;
    }
  }

  // edge_attr passthrough (second tuple element)
  hipMemcpyAsync((float*)d_out + (size_t)N_NODES * DIM, eattr,
                 (size_t)N_EDGES * 16 * 4, hipMemcpyDeviceToDevice, stream);
}